// Round 6
// baseline (520.823 us; speedup 1.0000x reference)
//
#include <hip/hip_runtime.h>
#include <math.h>

#define NCLS  100
#define ITERS 100

typedef _Float16 h2 __attribute__((ext_vector_type(2)));

#if __has_builtin(__builtin_amdgcn_rcpf)
__device__ __forceinline__ float fast_rcp(float x) { return __builtin_amdgcn_rcpf(x); }
#else
__device__ __forceinline__ float fast_rcp(float x) { return 1.0f / x; }
#endif

#if __has_builtin(__builtin_amdgcn_exp2f)
__device__ __forceinline__ float fast_exp2(float x) { return __builtin_amdgcn_exp2f(x); }
#else
__device__ __forceinline__ float fast_exp2(float x) { return exp2f(x); }
#endif

__device__ __forceinline__ float rlane(float v, int l) {
    return __int_as_float(__builtin_amdgcn_readlane(__float_as_int(v), l));
}
// pack two f32 -> f16x2 (v_cvt_pkrtz_f16_f32)
__device__ __forceinline__ h2 pack_h2(float x, float y) {
    return __builtin_bit_cast(h2, __builtin_amdgcn_cvt_pkrtz(x, y));
}
__device__ __forceinline__ h2 as_h2(unsigned u) {
    return __builtin_bit_cast(h2, u);
}

#if __has_builtin(__builtin_amdgcn_fdot2)
__device__ __forceinline__ float fdot2(h2 a, h2 b, float c) {
    return __builtin_amdgcn_fdot2(a, b, c, false);   // v_dot2_f32_f16
}
#else
__device__ __forceinline__ float fdot2(h2 a, h2 b, float c) {
    c = fmaf((float)a.x, (float)b.x, c);
    c = fmaf((float)a.y, (float)b.y, c);
    return c;
}
#endif

__device__ __forceinline__ float wave_sum(float v) {
#pragma unroll
    for (int m = 32; m > 0; m >>= 1) v += __shfl_xor(v, m, 64);
    return v;
}
__device__ __forceinline__ float wave_max(float v) {
#pragma unroll
    for (int m = 32; m > 0; m >>= 1) v = fmaxf(v, __shfl_xor(v, m, 64));
    return v;
}

// (K x)_{i0,i1}; x distributed: lane p holds x[2p] (s0), x[2p+1] (s1), > 0.
// Single K window khE[m] = {w(i1-2m), w(i1-2m-1)}, m=0..50 (51 VGPRs).
// Row i1:  dot2(khE[m], {x_2m, x_2m+1})          -- broadcast sx_m (SGPR)
// Row i0:  dot2(khE[m], {x_2m-1, x_2m})          -- yp_m = s_pack_lh(sx_{m-1}, sx_m)
//   since khE[m] = {w(i0-(2m-1)), w(i0-2m)}. SALU forms yp; zero VALU cost.
// x range-compressed by wave max into f16 (exact rescale multiplied back).
#define MATVEC(dst0, dst1, s0, s1)                                            \
    {                                                                         \
        float mxv = wave_max(fmaxf(s0, s1));                                  \
        float inv = fast_rcp(mxv);                                            \
        unsigned xp = __builtin_bit_cast(unsigned, pack_h2(s0 * inv, s1 * inv)); \
        float A0 = 0.f, B0 = 0.f, A1 = 0.f, B1 = 0.f;                         \
        unsigned sprev = 0u;                                                  \
        _Pragma("unroll")                                                     \
        for (int m = 0; m < 50; m += 2) {                                     \
            unsigned sx0 = (unsigned)__builtin_amdgcn_readlane((int)xp, m);   \
            unsigned yp0 = (sprev >> 16) | (sx0 << 16);                       \
            A1 = fdot2(khE[m], as_h2(sx0), A1);                               \
            A0 = fdot2(khE[m], as_h2(yp0), A0);                               \
            unsigned sx1 = (unsigned)__builtin_amdgcn_readlane((int)xp, m + 1); \
            unsigned yp1 = (sx0 >> 16) | (sx1 << 16);                         \
            B1 = fdot2(khE[m + 1], as_h2(sx1), B1);                           \
            B0 = fdot2(khE[m + 1], as_h2(yp1), B0);                           \
            sprev = sx1;                                                      \
        }                                                                     \
        A0 = fdot2(khE[50], as_h2(sprev >> 16), A0); /* w(i0-99)*x_99 */      \
        dst0 = (A0 + B0) * mxv;                                               \
        dst1 = (A1 + B1) * mxv;                                               \
    }

extern "C" __global__ void sk_zero_out(float* out) { out[0] = 0.0f; }

extern "C" __global__ void __launch_bounds__(64)
sk_sinkhorn(const float* __restrict__ pred, const int* __restrict__ target,
            float* __restrict__ out, int rows)
{
    const int r  = blockIdx.x;
    const int l  = threadIdx.x;
    const int i0 = 2 * l;
    const int i1 = i0 + 1;
    const bool active = (i0 < NCLS);

    // ---- marginals: mu = normalize(softmax(pred_row) + STAB) ----
    const float* prow = pred + (size_t)r * NCLS;
    float p0 = active ? prow[i0] : -3.4e38f;
    float p1 = active ? prow[i1] : -3.4e38f;
    float mx = wave_max(fmaxf(p0, p1));
    float e0 = active ? expf(p0 - mx) : 0.0f;
    float e1 = active ? expf(p1 - mx) : 0.0f;
    float S    = wave_sum(e0 + e1);
    float invS = 1.0f / S;
    float mur0 = active ? (e0 * invS + 1e-6f) : 0.0f;
    float mur1 = active ? (e1 * invS + 1e-6f) : 0.0f;
    float Smu  = wave_sum(mur0 + mur1);
    float invM = 1.0f / Smu;
    float mu0 = mur0 * invM, mu1 = mur1 * invM;

    // ---- nu = normalize(one_hot(target) + STAB) ----
    int   tgt = target[r];
    float nr0 = active ? (((i0 == tgt) ? 1.0f : 0.0f) + 1e-6f) : 0.0f;
    float nr1 = active ? (((i1 == tgt) ? 1.0f : 0.0f) + 1e-6f) : 0.0f;
    float Snu  = wave_sum(nr0 + nr1);
    float invN = 1.0f / Snu;
    float nu0 = nr0 * invN, nu1 = nr1 * invN;

    // ---- Toeplitz K window, f16 pairs (51 regs): w(d) = exp2(c2*d^2) ----
    // C_ij = (i-j)^2/9801, K = exp(-10*C); c2 = -10*log2(e)/9801
    const float c2 = -14.4269504089f / 9801.0f;
    h2 khE[51];
#pragma unroll
    for (int m = 0; m <= 50; ++m) {
        int   e  = i1 - 2 * m;
        float w0 = fast_exp2(c2 * (float)(e * e));             // w(i1-2m)
        float w1 = fast_exp2(c2 * (float)((e - 1) * (e - 1))); // w(i1-2m-1)
        khE[m] = pack_h2(w0, w1);
    }

    // ---- Sinkhorn scaling, exp domain: a = mu/(K b), b = nu/(K a) ----
    float a0 = 0.f, a1 = 0.f, b0 = 1.0f, b1 = 1.0f;
#pragma unroll 1
    for (int it = 0; it < ITERS; ++it) {
        float t0, t1;
        MATVEC(t0, t1, b0, b1);
        a0 = mu0 * fast_rcp(t0);
        a1 = mu1 * fast_rcp(t1);
        float s0, s1;
        MATVEC(s0, s1, a0, a1);
        b0 = nu0 * fast_rcp(s0);
        b1 = nu1 * fast_rcp(s1);
    }

    // ---- epilogue (fp32): P = aKb + STAB, renorm rows to mu, cols to nu ----
    float t0, t1;
    MATVEC(t0, t1, b0, b1);
    float row0 = fmaf(a0, t0, (float)NCLS * 1e-6f);
    float row1 = fmaf(a1, t1, (float)NCLS * 1e-6f);
    float scl0 = mu0 * fast_rcp(row0);   // inactive lanes: mu=0 -> 0
    float scl1 = mu1 * fast_rcp(row1);
    float ap0 = a0 * scl0, ap1 = a1 * scl1;
    float Ssum = wave_sum(scl0 + scl1);

    // q_j=(K a')_j, mm_j=((K.C) a')_j, cs_j=(C scl)_j at j = i0, i1
    // K recomputed in fp32 via exp2 (runs once; khE regs dead here).
    float q0 = 0.f, q1 = 0.f, mm0 = 0.f, mm1 = 0.f, cs0 = 0.f, cs1 = 0.f;
    const float fi0 = (float)i0;
    const float inv = 1.0f / 9801.0f;
    const float c3  = -14.4269504089f;   // K = exp2(c3 * C)
#pragma unroll
    for (int j = 0; j < NCLS; j += 2) {
        float alo = rlane(ap0,  j >> 1);
        float ahi = rlane(ap1,  j >> 1);
        float slo = rlane(scl0, j >> 1);
        float shi = rlane(scl1, j >> 1);
        float d0  = fi0 - (float)j;
        float em  = (d0 - 1.0f) * (d0 - 1.0f) * inv;  // C(i0, j+1)
        float e0c = d0 * d0 * inv;                    // C(i0,j) = C(i1,j+1)
        float ep  = (d0 + 1.0f) * (d0 + 1.0f) * inv;  // C(i1, j)
        float klo0 = fast_exp2(c3 * e0c);             // K[i0][j]
        float khi0 = fast_exp2(c3 * em);              // K[i0][j+1]
        float klo1 = fast_exp2(c3 * ep);              // K[i1][j]
        float khi1 = klo0;                            // K[i1][j+1]
        q0  = fmaf(klo0, alo, q0);        q0  = fmaf(khi0, ahi, q0);
        q1  = fmaf(klo1, alo, q1);        q1  = fmaf(khi1, ahi, q1);
        mm0 = fmaf(klo0 * e0c, alo, mm0); mm0 = fmaf(khi0 * em,  ahi, mm0);
        mm1 = fmaf(klo1 * ep,  alo, mm1); mm1 = fmaf(khi1 * e0c, ahi, mm1);
        cs0 = fmaf(e0c, slo, cs0);        cs0 = fmaf(em,  shi, cs0);
        cs1 = fmaf(ep,  slo, cs1);        cs1 = fmaf(e0c, shi, cs1);
    }

    // colsum_j = b_j*q_j + STAB*sum(scl); cost = sum_j nu_j/colsum_j*(b_j*mm_j + STAB*cs_j)
    float z = 0.0f;
    if (active) {
        float col0 = fmaf(b0, q0, 1e-6f * Ssum);
        float col1 = fmaf(b1, q1, 1e-6f * Ssum);
        float in0  = fmaf(b0, mm0, 1e-6f * cs0);
        float in1  = fmaf(b1, mm1, 1e-6f * cs1);
        z = nu0 * fast_rcp(col0) * in0 + nu1 * fast_rcp(col1) * in1;
    }
    float rc = wave_sum(z);
    if (l == 0) atomicAdd(out, rc / (float)rows);
}

extern "C" void kernel_launch(void* const* d_in, const int* in_sizes, int n_in,
                              void* d_out, int out_size, void* d_ws, size_t ws_size,
                              hipStream_t stream)
{
    const float* pred   = (const float*)d_in[0];
    const int*   target = (const int*)d_in[1];
    float*       out    = (float*)d_out;
    const int    rows   = in_sizes[0] / NCLS;   // 4096

    hipLaunchKernelGGL(sk_zero_out, dim3(1), dim3(1), 0, stream, out);
    hipLaunchKernelGGL(sk_sinkhorn, dim3(rows), dim3(64), 0, stream,
                       pred, target, out, rows);
}

// Round 7
// 229.362 us; speedup vs baseline: 2.2707x; 2.2707x over previous
//
#include <hip/hip_runtime.h>
#include <math.h>

#define NCLS   100
#define ITERS  100
#define RPB    16            // batch rows per block (MFMA M)
#define XS     136           // LDS x row stride, bf16 elems (272B: 16B-aligned, 2-way banks)
#define XBUF   (RPB * XS)

typedef short  bf16x8 __attribute__((ext_vector_type(8)));   // 8 bf16 in 4 VGPRs
typedef float  f32x4  __attribute__((ext_vector_type(4)));

#if __has_builtin(__builtin_amdgcn_rcpf)
__device__ __forceinline__ float fast_rcp(float x) { return __builtin_amdgcn_rcpf(x); }
#else
__device__ __forceinline__ float fast_rcp(float x) { return 1.0f / x; }
#endif

#if __has_builtin(__builtin_amdgcn_exp2f)
__device__ __forceinline__ float fast_exp2(float x) { return __builtin_amdgcn_exp2f(x); }
#else
__device__ __forceinline__ float fast_exp2(float x) { return exp2f(x); }
#endif

__device__ __forceinline__ float rlane(float v, int l) {
    return __int_as_float(__builtin_amdgcn_readlane(__float_as_int(v), l));
}
__device__ __forceinline__ unsigned bf16_rne(float f) {   // f32 -> bf16 bits, RNE
    unsigned u = __float_as_uint(f);
    return (u + 0x7FFFu + ((u >> 16) & 1u)) >> 16;
}
__device__ __forceinline__ float wave_sum(float v) {
#pragma unroll
    for (int m = 32; m > 0; m >>= 1) v += __shfl_xor(v, m, 64);
    return v;
}
__device__ __forceinline__ float wave_max(float v) {
#pragma unroll
    for (int m = 32; m > 0; m >>= 1) v = fmaxf(v, __shfl_xor(v, m, 64));
    return v;
}

extern "C" __global__ void sk_zero_out(float* out) { out[0] = 0.0f; }

// ---------------------------------------------------------------------------
// Kernel 1: 200 Sinkhorn half-iterations as 16x16x32 bf16 MFMA GEMMs.
// Block = 16 batch rows, 4 waves; wave w owns N-tiles {2w, 2w+1} (N padded 128).
// K (symmetric Toeplitz, w(d)=exp2(c2*d^2)) lives in registers as B-frags.
// x ping-pongs through LDS bf16 [16][XS]. Final a (it=198) / b (199) -> ws f32.
// ---------------------------------------------------------------------------
extern "C" __global__ void __launch_bounds__(256)
sk_iter_mfma(const float* __restrict__ pred, const int* __restrict__ target,
             float* __restrict__ wsA, float* __restrict__ wsB)
{
    __shared__ short xs[2 * XBUF];
    __shared__ float muL[RPB * 104];

    const int tid  = threadIdx.x;
    const int lane = tid & 63;
    const int wave = tid >> 6;        // 0..3
    const int quad = lane >> 4;       // 0..3
    const int lc   = lane & 15;
    const int row0 = blockIdx.x * RPB;

    // ---- mu = normalize(softmax(pred_row) + STAB): 16 threads per row ----
    {
        const int r = tid >> 4;       // 0..15 (4 rows per wave; shfl groups of 16)
        const int c = tid & 15;
        const float* p = pred + (size_t)(row0 + r) * NCLS;
        float v[7];
        float mx = -3.4e38f;
#pragma unroll
        for (int q = 0; q < 7; ++q) {
            int j = c + q * 16;
            v[q] = (j < NCLS) ? p[j] : -3.4e38f;
            mx = fmaxf(mx, v[q]);
        }
#pragma unroll
        for (int m = 8; m >= 1; m >>= 1) mx = fmaxf(mx, __shfl_xor(mx, m, 64));
        float s = 0.f;
#pragma unroll
        for (int q = 0; q < 7; ++q) {
            v[q] = (c + q * 16 < NCLS) ? expf(v[q] - mx) : 0.f;
            s += v[q];
        }
#pragma unroll
        for (int m = 8; m >= 1; m >>= 1) s += __shfl_xor(s, m, 64);
        float invS = 1.f / s;
        float s2 = 0.f;
#pragma unroll
        for (int q = 0; q < 7; ++q) {
            if (c + q * 16 < NCLS) { v[q] = v[q] * invS + 1e-6f; s2 += v[q]; }
        }
#pragma unroll
        for (int m = 8; m >= 1; m >>= 1) s2 += __shfl_xor(s2, m, 64);
        float invM = 1.f / s2;
#pragma unroll
        for (int q = 0; q < 7; ++q) {
            int j = c + q * 16;
            if (j < NCLS) muL[r * 104 + j] = v[q] * invM;
        }
    }

    // ---- this wave's N-columns ----
    const int t0n = (2 * wave) * 16 + lc;
    const int t1n = (2 * wave + 1) * 16 + lc;
    const float bias0 = (t0n >= NCLS) ? 1.0f : 0.0f;   // keep rcp input > 0 on pad cols
    const float bias1 = (t1n >= NCLS) ? 1.0f : 0.0f;

    // ---- static B-fragments: B[k=quad*8+j][n=lane&15] = w(k-n), bf16 ----
    const float c2 = -14.4269504089f / 9801.0f;        // -10*log2(e)/9801
    bf16x8 B0[4], B1[4];
#pragma unroll
    for (int s = 0; s < 4; ++s) {
#pragma unroll
        for (int j = 0; j < 8; ++j) {
            int k  = s * 32 + quad * 8 + j;
            int d0 = k - t0n;
            int d1 = k - t1n;
            B0[s][j] = (short)bf16_rne(fast_exp2(c2 * (float)(d0 * d0)));
            B1[s][j] = (short)bf16_rne(fast_exp2(c2 * (float)(d1 * d1)));
        }
    }

    __syncthreads();   // muL ready

    // ---- marginal fragments in C-layout (row m = quad*4+r, col = t*16+lc) ----
    f32x4 mu0f, mu1f, nu0f, nu1f;
    const float invN = 1.0f / (1.0f + (float)NCLS * 1e-6f);
#pragma unroll
    for (int r = 0; r < 4; ++r) {
        int m = quad * 4 + r;
        mu0f[r] = (t0n < NCLS) ? muL[m * 104 + t0n] : 0.f;
        mu1f[r] = (t1n < NCLS) ? muL[m * 104 + t1n] : 0.f;
        int tg = (int)target[row0 + m];
        nu0f[r] = (t0n < NCLS) ? ((((t0n == tg) ? 1.f : 0.f) + 1e-6f) * invN) : 0.f;
        nu1f[r] = (t1n < NCLS) ? ((((t1n == tg) ? 1.f : 0.f) + 1e-6f) * invN) : 0.f;
    }

    // ---- init x = b0 = 1 (cols < 100), 0 on pad cols; buffer 0 ----
    {
        const short one = (short)0x3F80;   // bf16(1.0)
#pragma unroll
        for (int r = 0; r < 4; ++r) {
            int m = quad * 4 + r;
            xs[m * XS + t0n] = (t0n < NCLS) ? one : (short)0;
            xs[m * XS + t1n] = (t1n < NCLS) ? one : (short)0;
        }
    }
    __syncthreads();

    // ---- 200 half-iterations: x_new = marg ⊘ (K x) ----
    const size_t gbase = (size_t)row0 * 128;
    for (int it = 0; it < 2 * ITERS; ++it) {
        const short* cur = xs + (it & 1) * XBUF;
        short*       nxt = xs + ((it + 1) & 1) * XBUF;

        bf16x8 A[4];
#pragma unroll
        for (int s = 0; s < 4; ++s)
            A[s] = *(const bf16x8*)(cur + lc * XS + s * 32 + quad * 8);

        f32x4 acc0 = {0.f, 0.f, 0.f, 0.f};
        f32x4 acc1 = {0.f, 0.f, 0.f, 0.f};
#pragma unroll
        for (int s = 0; s < 4; ++s) {
            acc0 = __builtin_amdgcn_mfma_f32_16x16x32_bf16(A[s], B0[s], acc0, 0, 0, 0);
            acc1 = __builtin_amdgcn_mfma_f32_16x16x32_bf16(A[s], B1[s], acc1, 0, 0, 0);
        }

        const bool odd = (it & 1) != 0;
#pragma unroll
        for (int r = 0; r < 4; ++r) {
            int m = quad * 4 + r;
            float mg0 = odd ? nu0f[r] : mu0f[r];
            float mg1 = odd ? nu1f[r] : mu1f[r];
            float x0 = mg0 * fast_rcp(acc0[r] + bias0);
            float x1 = mg1 * fast_rcp(acc1[r] + bias1);
            nxt[m * XS + t0n] = (short)bf16_rne(x0);
            nxt[m * XS + t1n] = (short)bf16_rne(x1);
            if (it == 2 * ITERS - 2) {          // final a
                wsA[gbase + m * 128 + t0n] = x0;
                wsA[gbase + m * 128 + t1n] = x1;
            } else if (it == 2 * ITERS - 1) {   // final b
                wsB[gbase + m * 128 + t0n] = x0;
                wsB[gbase + m * 128 + t1n] = x1;
            }
        }
        __syncthreads();
    }
}

// ---------------------------------------------------------------------------
// Kernel 2: fp32 epilogue (one wave per batch row) — round-6-verified math.
// P = a K b + STAB, rows renormed to mu, cols to nu; cost = sum(P*C); mean.
// K recomputed via exp2 (runs once per row).
// ---------------------------------------------------------------------------
extern "C" __global__ void __launch_bounds__(64)
sk_epilogue(const float* __restrict__ pred, const int* __restrict__ target,
            const float* __restrict__ wsA, const float* __restrict__ wsB,
            float* __restrict__ out, int rows)
{
    const int r  = blockIdx.x;
    const int l  = threadIdx.x;
    const int i0 = 2 * l;
    const int i1 = i0 + 1;
    const bool active = (i0 < NCLS);

    // ---- mu ----
    const float* prow = pred + (size_t)r * NCLS;
    float p0 = active ? prow[i0] : -3.4e38f;
    float p1 = active ? prow[i1] : -3.4e38f;
    float mx = wave_max(fmaxf(p0, p1));
    float e0 = active ? expf(p0 - mx) : 0.0f;
    float e1 = active ? expf(p1 - mx) : 0.0f;
    float S    = wave_sum(e0 + e1);
    float invS = 1.0f / S;
    float mur0 = active ? (e0 * invS + 1e-6f) : 0.0f;
    float mur1 = active ? (e1 * invS + 1e-6f) : 0.0f;
    float Smu  = wave_sum(mur0 + mur1);
    float invM = 1.0f / Smu;
    float mu0 = mur0 * invM, mu1 = mur1 * invM;

    // ---- nu ----
    int   tgt = (int)target[r];
    float nr0 = active ? (((i0 == tgt) ? 1.0f : 0.0f) + 1e-6f) : 0.0f;
    float nr1 = active ? (((i1 == tgt) ? 1.0f : 0.0f) + 1e-6f) : 0.0f;
    float Snu  = wave_sum(nr0 + nr1);
    float invN = 1.0f / Snu;
    float nu0 = nr0 * invN, nu1 = nr1 * invN;

    // ---- converged scalings from ws ----
    const float* Arow = wsA + (size_t)r * 128;
    const float* Brow = wsB + (size_t)r * 128;
    float a0 = Arow[i0], a1 = Arow[i1];
    float b0 = Brow[i0], b1 = Brow[i1];

    const float inv = 1.0f / 9801.0f;
    const float c3  = -14.4269504089f;   // K = exp2(c3 * C)
    const float fi0 = (float)i0;

    // ---- pass 1: t = K b (rows i0, i1) ----
    float t0 = 0.f, t1 = 0.f;
#pragma unroll
    for (int j = 0; j < NCLS; j += 2) {
        float blo = rlane(b0, j >> 1);
        float bhi = rlane(b1, j >> 1);
        float d0  = fi0 - (float)j;
        float em  = (d0 - 1.0f) * (d0 - 1.0f) * inv;  // C(i0, j+1)
        float e0c = d0 * d0 * inv;                    // C(i0,j) = C(i1,j+1)
        float ep  = (d0 + 1.0f) * (d0 + 1.0f) * inv;  // C(i1, j)
        float wm = fast_exp2(c3 * em);
        float w0 = fast_exp2(c3 * e0c);
        float wp = fast_exp2(c3 * ep);
        t0 = fmaf(w0, blo, t0); t0 = fmaf(wm, bhi, t0);
        t1 = fmaf(wp, blo, t1); t1 = fmaf(w0, bhi, t1);
    }

    // ---- row renorm ----
    float row0 = fmaf(a0, t0, (float)NCLS * 1e-6f);
    float row1 = fmaf(a1, t1, (float)NCLS * 1e-6f);
    float scl0 = mu0 * fast_rcp(row0);   // inactive lanes: mu=0 -> 0
    float scl1 = mu1 * fast_rcp(row1);
    float ap0 = a0 * scl0, ap1 = a1 * scl1;
    float Ssum = wave_sum(scl0 + scl1);

    // ---- pass 2: q=(K a'), mm=((K.C) a'), cs=(C scl) at j = i0, i1 ----
    float q0 = 0.f, q1 = 0.f, mm0 = 0.f, mm1 = 0.f, cs0 = 0.f, cs1 = 0.f;
#pragma unroll
    for (int j = 0; j < NCLS; j += 2) {
        float alo = rlane(ap0,  j >> 1);
        float ahi = rlane(ap1,  j >> 1);
        float slo = rlane(scl0, j >> 1);
        float shi = rlane(scl1, j >> 1);
        float d0  = fi0 - (float)j;
        float em  = (d0 - 1.0f) * (d0 - 1.0f) * inv;
        float e0c = d0 * d0 * inv;
        float ep  = (d0 + 1.0f) * (d0 + 1.0f) * inv;
        float klo0 = fast_exp2(c3 * e0c);             // K[i0][j]
        float khi0 = fast_exp2(c3 * em);              // K[i0][j+1]
        float klo1 = fast_exp2(c3 * ep);              // K[i1][j]
        float khi1 = klo0;                            // K[i1][j+1]
        q0  = fmaf(klo0, alo, q0);        q0  = fmaf(khi0, ahi, q0);
        q1  = fmaf(klo1, alo, q1);        q1  = fmaf(khi1, ahi, q1);
        mm0 = fmaf(klo0 * e0c, alo, mm0); mm0 = fmaf(khi0 * em,  ahi, mm0);
        mm1 = fmaf(klo1 * ep,  alo, mm1); mm1 = fmaf(khi1 * e0c, ahi, mm1);
        cs0 = fmaf(e0c, slo, cs0);        cs0 = fmaf(em,  shi, cs0);
        cs1 = fmaf(ep,  slo, cs1);        cs1 = fmaf(e0c, shi, cs1);
    }

    // ---- column renorm + cost ----
    float z = 0.0f;
    if (active) {
        float col0 = fmaf(b0, q0, 1e-6f * Ssum);
        float col1 = fmaf(b1, q1, 1e-6f * Ssum);
        float in0  = fmaf(b0, mm0, 1e-6f * cs0);
        float in1  = fmaf(b1, mm1, 1e-6f * cs1);
        z = nu0 * fast_rcp(col0) * in0 + nu1 * fast_rcp(col1) * in1;
    }
    float rc = wave_sum(z);
    if (l == 0) atomicAdd(out, rc / (float)rows);
}

extern "C" void kernel_launch(void* const* d_in, const int* in_sizes, int n_in,
                              void* d_out, int out_size, void* d_ws, size_t ws_size,
                              hipStream_t stream)
{
    const float* pred   = (const float*)d_in[0];
    const int*   target = (const int*)d_in[1];
    float*       out    = (float*)d_out;
    const int    rows   = in_sizes[0] / NCLS;   // 4096

    float* wsA = (float*)d_ws;                  // [rows][128] f32
    float* wsB = wsA + (size_t)rows * 128;      // [rows][128] f32 (4 MB total)

    hipLaunchKernelGGL(sk_zero_out, dim3(1), dim3(1), 0, stream, out);
    hipLaunchKernelGGL(sk_iter_mfma, dim3(rows / RPB), dim3(256), 0, stream,
                       pred, target, wsA, wsB);
    hipLaunchKernelGGL(sk_epilogue, dim3(rows), dim3(64), 0, stream,
                       pred, target, wsA, wsB, out, rows);
}

// Round 8
// 125.892 us; speedup vs baseline: 4.1371x; 1.8219x over previous
//
#include <hip/hip_runtime.h>
#include <math.h>

#define NCLS   100
#define ITERS  100
#define RPB    16            // batch rows per block (MFMA M)
#define XS     136           // LDS x row stride, bf16 elems
#define XBUF   (RPB * XS)

typedef short  bf16x8 __attribute__((ext_vector_type(8)));   // 8 bf16 in 4 VGPRs
typedef float  f32x4  __attribute__((ext_vector_type(4)));

#if __has_builtin(__builtin_amdgcn_rcpf)
__device__ __forceinline__ float fast_rcp(float x) { return __builtin_amdgcn_rcpf(x); }
#else
__device__ __forceinline__ float fast_rcp(float x) { return 1.0f / x; }
#endif

#if __has_builtin(__builtin_amdgcn_exp2f)
__device__ __forceinline__ float fast_exp2(float x) { return __builtin_amdgcn_exp2f(x); }
#else
__device__ __forceinline__ float fast_exp2(float x) { return exp2f(x); }
#endif

__device__ __forceinline__ unsigned bf16_rne(float f) {   // f32 -> bf16 bits, RNE
    unsigned u = __float_as_uint(f);
    return (u + 0x7FFFu + ((u >> 16) & 1u)) >> 16;
}
__device__ __forceinline__ float wave_sum(float v) {
#pragma unroll
    for (int m = 32; m > 0; m >>= 1) v += __shfl_xor(v, m, 64);
    return v;
}

extern "C" __global__ void sk_zero_out(float* out) { out[0] = 0.0f; }

// ---------------------------------------------------------------------------
// Fully fused: 200 Sinkhorn half-iterations as 16x16x32 bf16 MFMA GEMMs,
// then the plan-renorm cost epilogue in the same block (3 more MFMA rounds
// against Toeplitz-generated K, K.C and C fragments). No workspace.
// Block = 16 batch rows, 4 waves; wave w owns N-tiles {2w, 2w+1} (N pad 128).
// ---------------------------------------------------------------------------
extern "C" __global__ void __launch_bounds__(256)
sk_fused(const float* __restrict__ pred, const int* __restrict__ target,
         float* __restrict__ out, int rows)
{
    __shared__ short xs[2 * XBUF];
    __shared__ __align__(16) float aux[RPB * 104];   // muL pre-loop; SsumP/zP/sclS post

    const int tid  = threadIdx.x;
    const int lane = tid & 63;
    const int wave = tid >> 6;        // 0..3
    const int quad = lane >> 4;       // 0..3
    const int lc   = lane & 15;
    const int row0 = blockIdx.x * RPB;

    // ---- mu = normalize(softmax(pred_row) + STAB): 16 threads per row ----
    {
        const int r = tid >> 4;       // 0..15
        const int c = tid & 15;
        const float* p = pred + (size_t)(row0 + r) * NCLS;
        float v[7];
        float mx = -3.4e38f;
#pragma unroll
        for (int q = 0; q < 7; ++q) {
            int j = c + q * 16;
            v[q] = (j < NCLS) ? p[j] : -3.4e38f;
            mx = fmaxf(mx, v[q]);
        }
#pragma unroll
        for (int m = 8; m >= 1; m >>= 1) mx = fmaxf(mx, __shfl_xor(mx, m, 64));
        float s = 0.f;
#pragma unroll
        for (int q = 0; q < 7; ++q) {
            v[q] = (c + q * 16 < NCLS) ? expf(v[q] - mx) : 0.f;
            s += v[q];
        }
#pragma unroll
        for (int m = 8; m >= 1; m >>= 1) s += __shfl_xor(s, m, 64);
        float invS = 1.f / s;
        float s2 = 0.f;
#pragma unroll
        for (int q = 0; q < 7; ++q) {
            if (c + q * 16 < NCLS) { v[q] = v[q] * invS + 1e-6f; s2 += v[q]; }
        }
#pragma unroll
        for (int m = 8; m >= 1; m >>= 1) s2 += __shfl_xor(s2, m, 64);
        float invM = 1.f / s2;
#pragma unroll
        for (int q = 0; q < 7; ++q) {
            int j = c + q * 16;
            if (j < NCLS) aux[r * 104 + j] = v[q] * invM;
        }
    }

    // ---- this wave's N-columns ----
    const int t0n = (2 * wave) * 16 + lc;
    const int t1n = (2 * wave + 1) * 16 + lc;
    const float bias0 = (t0n >= NCLS) ? 1.0f : 0.0f;   // keep rcp input > 0 on pad cols
    const float bias1 = (t1n >= NCLS) ? 1.0f : 0.0f;

    // ---- static B-fragments: B[k=quad*8+j][n] = w(k-n), bf16, Toeplitz ----
    const float c2 = -14.4269504089f / 9801.0f;        // -10*log2(e)/9801
    bf16x8 B0[4], B1[4];
#pragma unroll
    for (int s = 0; s < 4; ++s) {
#pragma unroll
        for (int j = 0; j < 8; ++j) {
            int k  = s * 32 + quad * 8 + j;
            int d0 = k - t0n;
            int d1 = k - t1n;
            B0[s][j] = (short)bf16_rne(fast_exp2(c2 * (float)(d0 * d0)));
            B1[s][j] = (short)bf16_rne(fast_exp2(c2 * (float)(d1 * d1)));
        }
    }

    __syncthreads();   // muL ready

    // ---- marginal fragments in C-layout (row m = quad*4+r, col n) ----
    f32x4 mu0f, mu1f, nu0f, nu1f;
    const float invN = 1.0f / (1.0f + (float)NCLS * 1e-6f);
#pragma unroll
    for (int r = 0; r < 4; ++r) {
        int m = quad * 4 + r;
        mu0f[r] = (t0n < NCLS) ? aux[m * 104 + t0n] : 0.f;
        mu1f[r] = (t1n < NCLS) ? aux[m * 104 + t1n] : 0.f;
        int tg = (int)target[row0 + m];
        nu0f[r] = (t0n < NCLS) ? ((((t0n == tg) ? 1.f : 0.f) + 1e-6f) * invN) : 0.f;
        nu1f[r] = (t1n < NCLS) ? ((((t1n == tg) ? 1.f : 0.f) + 1e-6f) * invN) : 0.f;
    }

    // ---- init x = b0 = 1 (cols < 100), 0 on pad cols; buffer 0 ----
    {
        const short one = (short)0x3F80;   // bf16(1.0)
#pragma unroll
        for (int r = 0; r < 4; ++r) {
            int m = quad * 4 + r;
            xs[m * XS + t0n] = (t0n < NCLS) ? one : (short)0;
            xs[m * XS + t1n] = (t1n < NCLS) ? one : (short)0;
        }
    }
    __syncthreads();

    // ---- 200 half-iterations: x_new = marg ⊘ (K x) ----
    f32x4 aR0, aR1, bR0, bR1;   // final fp32 scalings captured at it=198/199
    for (int it = 0; it < 2 * ITERS; ++it) {
        const short* cur = xs + (it & 1) * XBUF;
        short*       nxt = xs + ((it + 1) & 1) * XBUF;

        bf16x8 A[4];
#pragma unroll
        for (int s = 0; s < 4; ++s)
            A[s] = *(const bf16x8*)(cur + lc * XS + s * 32 + quad * 8);

        f32x4 acc0 = {0.f, 0.f, 0.f, 0.f};
        f32x4 acc1 = {0.f, 0.f, 0.f, 0.f};
#pragma unroll
        for (int s = 0; s < 4; ++s) {
            acc0 = __builtin_amdgcn_mfma_f32_16x16x32_bf16(A[s], B0[s], acc0, 0, 0, 0);
            acc1 = __builtin_amdgcn_mfma_f32_16x16x32_bf16(A[s], B1[s], acc1, 0, 0, 0);
        }

        const bool odd = (it & 1) != 0;
#pragma unroll
        for (int r = 0; r < 4; ++r) {
            int m = quad * 4 + r;
            float mg0 = odd ? nu0f[r] : mu0f[r];
            float mg1 = odd ? nu1f[r] : mu1f[r];
            float x0 = mg0 * fast_rcp(acc0[r] + bias0);
            float x1 = mg1 * fast_rcp(acc1[r] + bias1);
            nxt[m * XS + t0n] = (short)bf16_rne(x0);
            nxt[m * XS + t1n] = (short)bf16_rne(x1);
            if (it == 2 * ITERS - 2) { aR0[r] = x0; aR1[r] = x1; }   // final a
            if (it == 2 * ITERS - 1) { bR0[r] = x0; bR1[r] = x1; }   // final b
        }
        __syncthreads();
    }
    // b (bf16) now in buffer 0; a dead (aR in regs).

    // ================= fused epilogue =================
    // t = K b  (same MFMA pattern, A from buffer 0)
    f32x4 t0a = {0.f, 0.f, 0.f, 0.f};
    f32x4 t1a = {0.f, 0.f, 0.f, 0.f};
    {
        bf16x8 A[4];
#pragma unroll
        for (int s = 0; s < 4; ++s)
            A[s] = *(const bf16x8*)(xs + lc * XS + s * 32 + quad * 8);
#pragma unroll
        for (int s = 0; s < 4; ++s) {
            t0a = __builtin_amdgcn_mfma_f32_16x16x32_bf16(A[s], B0[s], t0a, 0, 0, 0);
            t1a = __builtin_amdgcn_mfma_f32_16x16x32_bf16(A[s], B1[s], t1a, 0, 0, 0);
        }
    }

    // scl = mu / (a*t + n*STAB);  a' = a*scl.  Write a' (buf1) and scl bf16.
    float* SsumP = aux;                     // [4 waves][16 m] floats (256 B)
    float* zP    = aux + 64;                // [4] block-reduce slots
    short* sclS  = (short*)(aux + 128);     // [RPB][XS] bf16 (4352 B)
    short* apS   = xs + XBUF;               // buffer 1, a dead

    f32x4 sclv0, sclv1;
#pragma unroll
    for (int r = 0; r < 4; ++r) {
        int m = quad * 4 + r;
        float scl0 = mu0f[r] * fast_rcp(fmaf(aR0[r], t0a[r], (float)NCLS * 1e-6f));
        float scl1 = mu1f[r] * fast_rcp(fmaf(aR1[r], t1a[r], (float)NCLS * 1e-6f));
        sclv0[r] = scl0; sclv1[r] = scl1;             // pad cols: mu=0 -> 0
        apS[m * XS + t0n]  = (short)bf16_rne(aR0[r] * scl0);
        apS[m * XS + t1n]  = (short)bf16_rne(aR1[r] * scl1);
        sclS[m * XS + t0n] = (short)bf16_rne(scl0);
        sclS[m * XS + t1n] = (short)bf16_rne(scl1);
        // partial Ssum over this wave's 32 cols (16-lane quad reduce)
        float ps = scl0 + scl1;
#pragma unroll
        for (int w = 8; w >= 1; w >>= 1) ps += __shfl_xor(ps, w, 64);
        if (lc == 0) SsumP[wave * 16 + m] = ps;
    }
    __syncthreads();

    // Ssum[m] = sum over 4 waves
    f32x4 Ssum;
#pragma unroll
    for (int r = 0; r < 4; ++r) {
        int m = quad * 4 + r;
        Ssum[r] = SsumP[m] + SsumP[16 + m] + SsumP[32 + m] + SsumP[48 + m];
    }

    // B-frags for K.C and C (Toeplitz): KC(d) = K(d)*d^2/9801, C(d) = d^2/9801
    bf16x8 KC0[4], KC1[4], C0[4], C1[4];
    const float cinv = 1.0f / 9801.0f;
#pragma unroll
    for (int s = 0; s < 4; ++s) {
#pragma unroll
        for (int j = 0; j < 8; ++j) {
            int k  = s * 32 + quad * 8 + j;
            int d0 = k - t0n;
            int d1 = k - t1n;
            float c0 = (float)(d0 * d0) * cinv;
            float c1 = (float)(d1 * d1) * cinv;
            KC0[s][j] = (short)bf16_rne(fast_exp2(c2 * (float)(d0 * d0)) * c0);
            KC1[s][j] = (short)bf16_rne(fast_exp2(c2 * (float)(d1 * d1)) * c1);
            C0[s][j]  = (short)bf16_rne(c0);
            C1[s][j]  = (short)bf16_rne(c1);
        }
    }

    // q = K a',  mm = (K.C) a',  cs = C scl   (A-frags from apS / sclS)
    f32x4 q0 = {0,0,0,0}, q1 = {0,0,0,0};
    f32x4 m0 = {0,0,0,0}, m1 = {0,0,0,0};
    f32x4 s0 = {0,0,0,0}, s1 = {0,0,0,0};
    {
        bf16x8 Aa[4], As[4];
#pragma unroll
        for (int s = 0; s < 4; ++s) {
            Aa[s] = *(const bf16x8*)(apS  + lc * XS + s * 32 + quad * 8);
            As[s] = *(const bf16x8*)(sclS + lc * XS + s * 32 + quad * 8);
        }
#pragma unroll
        for (int s = 0; s < 4; ++s) {
            q0 = __builtin_amdgcn_mfma_f32_16x16x32_bf16(Aa[s], B0[s],  q0, 0, 0, 0);
            q1 = __builtin_amdgcn_mfma_f32_16x16x32_bf16(Aa[s], B1[s],  q1, 0, 0, 0);
            m0 = __builtin_amdgcn_mfma_f32_16x16x32_bf16(Aa[s], KC0[s], m0, 0, 0, 0);
            m1 = __builtin_amdgcn_mfma_f32_16x16x32_bf16(Aa[s], KC1[s], m1, 0, 0, 0);
            s0 = __builtin_amdgcn_mfma_f32_16x16x32_bf16(As[s], C0[s],  s0, 0, 0, 0);
            s1 = __builtin_amdgcn_mfma_f32_16x16x32_bf16(As[s], C1[s],  s1, 0, 0, 0);
        }
    }

    // cost: z = sum_j nu_j/(b_j q_j + STAB*Ssum) * (b_j mm_j + STAB*cs_j)
    float z = 0.f;
#pragma unroll
    for (int r = 0; r < 4; ++r) {
        float col0 = fmaf(bR0[r], q0[r], 1e-6f * Ssum[r]);
        float col1 = fmaf(bR1[r], q1[r], 1e-6f * Ssum[r]);
        float in0  = fmaf(bR0[r], m0[r], 1e-6f * s0[r]);
        float in1  = fmaf(bR1[r], m1[r], 1e-6f * s1[r]);
        z += nu0f[r] * fast_rcp(col0) * in0 + nu1f[r] * fast_rcp(col1) * in1;
    }
    z = wave_sum(z);
    if (lane == 0) zP[wave] = z;
    __syncthreads();
    if (tid == 0) {
        float tot = zP[0] + zP[1] + zP[2] + zP[3];
        atomicAdd(out, tot / (float)rows);
    }
}

extern "C" void kernel_launch(void* const* d_in, const int* in_sizes, int n_in,
                              void* d_out, int out_size, void* d_ws, size_t ws_size,
                              hipStream_t stream)
{
    const float* pred   = (const float*)d_in[0];
    const int*   target = (const int*)d_in[1];
    float*       out    = (float*)d_out;
    const int    rows   = in_sizes[0] / NCLS;   // 4096

    hipLaunchKernelGGL(sk_zero_out, dim3(1), dim3(1), 0, stream, out);
    hipLaunchKernelGGL(sk_fused, dim3(rows / RPB), dim3(256), 0, stream,
                       pred, target, out, rows);
}

// Round 9
// 122.449 us; speedup vs baseline: 4.2534x; 1.0281x over previous
//
#include <hip/hip_runtime.h>
#include <math.h>

#define NCLS   100
#define ITERS  100
#define RPB    16            // batch rows per block (MFMA M)
#define XS     136           // LDS x row stride, bf16 elems
#define XBUF   (RPB * XS)

typedef short  bf16x8 __attribute__((ext_vector_type(8)));   // 8 bf16 in 4 VGPRs
typedef float  f32x4  __attribute__((ext_vector_type(4)));

#if __has_builtin(__builtin_amdgcn_rcpf)
__device__ __forceinline__ float fast_rcp(float x) { return __builtin_amdgcn_rcpf(x); }
#else
__device__ __forceinline__ float fast_rcp(float x) { return 1.0f / x; }
#endif

#if __has_builtin(__builtin_amdgcn_exp2f)
__device__ __forceinline__ float fast_exp2(float x) { return __builtin_amdgcn_exp2f(x); }
#else
__device__ __forceinline__ float fast_exp2(float x) { return exp2f(x); }
#endif

__device__ __forceinline__ unsigned bf16_rne(float f) {   // f32 -> bf16 bits, RNE
    unsigned u = __float_as_uint(f);
    return (u + 0x7FFFu + ((u >> 16) & 1u)) >> 16;
}
__device__ __forceinline__ float wave_sum(float v) {
#pragma unroll
    for (int m = 32; m > 0; m >>= 1) v += __shfl_xor(v, m, 64);
    return v;
}

extern "C" __global__ void sk_zero_out(float* out) { out[0] = 0.0f; }

// ---------------------------------------------------------------------------
// Fully fused Sinkhorn: 200 half-iterations as 16x16x32 bf16 MFMA GEMMs plus
// the plan-renorm cost epilogue. 512 threads = 8 waves; wave w owns ONE
// 16-col N-tile (cols [16w,16w+16), N padded 128). Shorter per-wave chains
// (4 MFMAs as two 2-deep accumulator chains) + 2 waves/SIMD for latency
// overlap. K is Toeplitz, generated in registers; x ping-pongs through LDS.
// ---------------------------------------------------------------------------
extern "C" __global__ void __launch_bounds__(512)
sk_fused(const float* __restrict__ pred, const int* __restrict__ target,
         float* __restrict__ out, int rows)
{
    __shared__ short xs[2 * XBUF];
    __shared__ __align__(16) float aux[RPB * 104];   // muL pre-loop; SsumP/zP/sclS post

    const int tid  = threadIdx.x;
    const int lane = tid & 63;
    const int wave = tid >> 6;        // 0..7
    const int quad = lane >> 4;       // 0..3
    const int lc   = lane & 15;
    const int row0 = blockIdx.x * RPB;

    // ---- mu = normalize(softmax(pred_row) + STAB): 32 threads per row ----
    {
        const int r = tid >> 5;       // 0..15
        const int c = tid & 31;
        const float* p = pred + (size_t)(row0 + r) * NCLS;
        float v[4];
        float mx = -3.4e38f;
#pragma unroll
        for (int q = 0; q < 4; ++q) {
            int j = c + q * 32;
            v[q] = (j < NCLS) ? p[j] : -3.4e38f;
            mx = fmaxf(mx, v[q]);
        }
#pragma unroll
        for (int m = 16; m >= 1; m >>= 1) mx = fmaxf(mx, __shfl_xor(mx, m, 64));
        float s = 0.f;
#pragma unroll
        for (int q = 0; q < 4; ++q) {
            v[q] = (c + q * 32 < NCLS) ? expf(v[q] - mx) : 0.f;
            s += v[q];
        }
#pragma unroll
        for (int m = 16; m >= 1; m >>= 1) s += __shfl_xor(s, m, 64);
        float invS = 1.f / s;
        float s2 = 0.f;
#pragma unroll
        for (int q = 0; q < 4; ++q) {
            if (c + q * 32 < NCLS) { v[q] = v[q] * invS + 1e-6f; s2 += v[q]; }
        }
#pragma unroll
        for (int m = 16; m >= 1; m >>= 1) s2 += __shfl_xor(s2, m, 64);
        float invM = 1.f / s2;
#pragma unroll
        for (int q = 0; q < 4; ++q) {
            int j = c + q * 32;
            if (j < NCLS) aux[r * 104 + j] = v[q] * invM;
        }
    }

    // ---- this wave's N-tile column ----
    const int tn = wave * 16 + lc;                 // 0..127
    const float bias0 = (tn >= NCLS) ? 1.0f : 0.0f;   // keep rcp input > 0 on pad cols

    // ---- static B-fragments: B[k=quad*8+j+32s][n=tn] = w(k-tn), bf16 ----
    const float c2 = -14.4269504089f / 9801.0f;    // -10*log2(e)/9801
    bf16x8 B0[4];
#pragma unroll
    for (int s = 0; s < 4; ++s) {
#pragma unroll
        for (int j = 0; j < 8; ++j) {
            int k = s * 32 + quad * 8 + j;
            int d = k - tn;
            B0[s][j] = (short)bf16_rne(fast_exp2(c2 * (float)(d * d)));
        }
    }

    __syncthreads();   // muL ready

    // ---- marginal fragments in C-layout (row m = quad*4+r, col tn) ----
    f32x4 mu0f, nu0f;
    const float invN = 1.0f / (1.0f + (float)NCLS * 1e-6f);
#pragma unroll
    for (int r = 0; r < 4; ++r) {
        int m = quad * 4 + r;
        mu0f[r] = (tn < NCLS) ? aux[m * 104 + tn] : 0.f;
        int tg = (int)target[row0 + m];
        nu0f[r] = (tn < NCLS) ? ((((tn == tg) ? 1.f : 0.f) + 1e-6f) * invN) : 0.f;
    }

    // ---- init x = b0 = 1 (cols < 100), 0 on pad cols; buffer 0 ----
    {
        const short one = (short)0x3F80;   // bf16(1.0)
#pragma unroll
        for (int r = 0; r < 4; ++r) {
            int m = quad * 4 + r;
            xs[m * XS + tn] = (tn < NCLS) ? one : (short)0;
        }
    }
    __syncthreads();

    // ---- 200 half-iterations: x_new = marg ⊘ (K x) ----
    f32x4 aR, bR;   // final fp32 scalings captured at it=198/199
    for (int it = 0; it < 2 * ITERS; ++it) {
        const short* cur = xs + (it & 1) * XBUF;
        short*       nxt = xs + ((it + 1) & 1) * XBUF;

        bf16x8 A[4];
#pragma unroll
        for (int s = 0; s < 4; ++s)
            A[s] = *(const bf16x8*)(cur + lc * XS + s * 32 + quad * 8);

        // two independent 2-deep MFMA chains -> shorter dependency chain
        f32x4 accA = {0.f, 0.f, 0.f, 0.f};
        f32x4 accB = {0.f, 0.f, 0.f, 0.f};
        accA = __builtin_amdgcn_mfma_f32_16x16x32_bf16(A[0], B0[0], accA, 0, 0, 0);
        accB = __builtin_amdgcn_mfma_f32_16x16x32_bf16(A[2], B0[2], accB, 0, 0, 0);
        accA = __builtin_amdgcn_mfma_f32_16x16x32_bf16(A[1], B0[1], accA, 0, 0, 0);
        accB = __builtin_amdgcn_mfma_f32_16x16x32_bf16(A[3], B0[3], accB, 0, 0, 0);
        f32x4 acc = accA + accB;

        const bool odd = (it & 1) != 0;
#pragma unroll
        for (int r = 0; r < 4; ++r) {
            int m = quad * 4 + r;
            float mg = odd ? nu0f[r] : mu0f[r];
            float x0 = mg * fast_rcp(acc[r] + bias0);
            nxt[m * XS + tn] = (short)bf16_rne(x0);
            if (it == 2 * ITERS - 2) aR[r] = x0;   // final a
            if (it == 2 * ITERS - 1) bR[r] = x0;   // final b
        }
        __syncthreads();
    }
    // b (bf16) now in buffer 0; a dead (aR in regs).

    // ================= fused epilogue =================
    // t = K b  (same MFMA pattern, A from buffer 0)
    f32x4 tA;
    {
        bf16x8 A[4];
#pragma unroll
        for (int s = 0; s < 4; ++s)
            A[s] = *(const bf16x8*)(xs + lc * XS + s * 32 + quad * 8);
        f32x4 t0 = {0.f, 0.f, 0.f, 0.f};
        f32x4 t1 = {0.f, 0.f, 0.f, 0.f};
        t0 = __builtin_amdgcn_mfma_f32_16x16x32_bf16(A[0], B0[0], t0, 0, 0, 0);
        t1 = __builtin_amdgcn_mfma_f32_16x16x32_bf16(A[2], B0[2], t1, 0, 0, 0);
        t0 = __builtin_amdgcn_mfma_f32_16x16x32_bf16(A[1], B0[1], t0, 0, 0, 0);
        t1 = __builtin_amdgcn_mfma_f32_16x16x32_bf16(A[3], B0[3], t1, 0, 0, 0);
        tA = t0 + t1;
    }

    // scl = mu / (a*t + n*STAB);  a' = a*scl.  Write a' (buf1) and scl bf16.
    float* SsumP = aux;                     // [8 waves][16 m] floats (512 B)
    float* zP    = aux + 128;               // [8] block-reduce slots
    short* sclS  = (short*)(aux + 136);     // [RPB][XS] bf16 (4352 B)
    short* apS   = xs + XBUF;               // buffer 1, a dead

#pragma unroll
    for (int r = 0; r < 4; ++r) {
        int m = quad * 4 + r;
        float scl = mu0f[r] * fast_rcp(fmaf(aR[r], tA[r], (float)NCLS * 1e-6f));
        apS[m * XS + tn]  = (short)bf16_rne(aR[r] * scl);
        sclS[m * XS + tn] = (short)bf16_rne(scl);
        // partial Ssum over this wave's 16 cols (16-lane quad reduce)
        float ps = scl;
#pragma unroll
        for (int w = 8; w >= 1; w >>= 1) ps += __shfl_xor(ps, w, 64);
        if (lc == 0) SsumP[wave * 16 + m] = ps;
    }
    __syncthreads();

    // Ssum[m] = sum over 8 waves
    f32x4 Ssum;
#pragma unroll
    for (int r = 0; r < 4; ++r) {
        int m = quad * 4 + r;
        float s = 0.f;
#pragma unroll
        for (int w = 0; w < 8; ++w) s += SsumP[w * 16 + m];
        Ssum[r] = s;
    }

    // B-frags for K.C and C (Toeplitz): KC(d) = K(d)*d^2/9801, C(d) = d^2/9801
    bf16x8 KC0[4], C0[4];
    const float cinv = 1.0f / 9801.0f;
#pragma unroll
    for (int s = 0; s < 4; ++s) {
#pragma unroll
        for (int j = 0; j < 8; ++j) {
            int k = s * 32 + quad * 8 + j;
            int d = k - tn;
            float c0 = (float)(d * d) * cinv;
            KC0[s][j] = (short)bf16_rne(fast_exp2(c2 * (float)(d * d)) * c0);
            C0[s][j]  = (short)bf16_rne(c0);
        }
    }

    // q = K a',  mm = (K.C) a',  cs = C scl   (A-frags from apS / sclS)
    f32x4 q0 = {0,0,0,0}, m0 = {0,0,0,0}, s0 = {0,0,0,0};
    {
        bf16x8 Aa[4], As[4];
#pragma unroll
        for (int s = 0; s < 4; ++s) {
            Aa[s] = *(const bf16x8*)(apS  + lc * XS + s * 32 + quad * 8);
            As[s] = *(const bf16x8*)(sclS + lc * XS + s * 32 + quad * 8);
        }
#pragma unroll
        for (int s = 0; s < 4; ++s) {
            q0 = __builtin_amdgcn_mfma_f32_16x16x32_bf16(Aa[s], B0[s],  q0, 0, 0, 0);
            m0 = __builtin_amdgcn_mfma_f32_16x16x32_bf16(Aa[s], KC0[s], m0, 0, 0, 0);
            s0 = __builtin_amdgcn_mfma_f32_16x16x32_bf16(As[s], C0[s],  s0, 0, 0, 0);
        }
    }

    // cost: z = sum_j nu_j/(b_j q_j + STAB*Ssum) * (b_j mm_j + STAB*cs_j)
    float z = 0.f;
#pragma unroll
    for (int r = 0; r < 4; ++r) {
        float col = fmaf(bR[r], q0[r], 1e-6f * Ssum[r]);
        float in  = fmaf(bR[r], m0[r], 1e-6f * s0[r]);
        z += nu0f[r] * fast_rcp(col) * in;
    }
    z = wave_sum(z);
    if (lane == 0) zP[wave] = z;
    __syncthreads();
    if (tid == 0) {
        float tot = 0.f;
#pragma unroll
        for (int w = 0; w < 8; ++w) tot += zP[w];
        atomicAdd(out, tot / (float)rows);
    }
}

extern "C" void kernel_launch(void* const* d_in, const int* in_sizes, int n_in,
                              void* d_out, int out_size, void* d_ws, size_t ws_size,
                              hipStream_t stream)
{
    const float* pred   = (const float*)d_in[0];
    const int*   target = (const int*)d_in[1];
    float*       out    = (float*)d_out;
    const int    rows   = in_sizes[0] / NCLS;   // 4096

    hipLaunchKernelGGL(sk_zero_out, dim3(1), dim3(1), 0, stream, out);
    hipLaunchKernelGGL(sk_fused, dim3(rows / RPB), dim3(512), 0, stream,
                       pred, target, out, rows);
}

// Round 10
// 73.936 us; speedup vs baseline: 7.0442x; 1.6561x over previous
//
#include <hip/hip_runtime.h>
#include <math.h>

#define NCLS   100
#define ITERS  100
#define RPB    16            // batch rows per block (MFMA M)
#define XS     136           // LDS x row stride, bf16 elems
#define XBUF   (RPB * XS)

typedef short  bf16x8 __attribute__((ext_vector_type(8)));   // 8 bf16 in 4 VGPRs
typedef float  f32x4  __attribute__((ext_vector_type(4)));

#if __has_builtin(__builtin_amdgcn_rcpf)
__device__ __forceinline__ float fast_rcp(float x) { return __builtin_amdgcn_rcpf(x); }
#else
__device__ __forceinline__ float fast_rcp(float x) { return 1.0f / x; }
#endif

#if __has_builtin(__builtin_amdgcn_exp2f)
__device__ __forceinline__ float fast_exp2(float x) { return __builtin_amdgcn_exp2f(x); }
#else
__device__ __forceinline__ float fast_exp2(float x) { return exp2f(x); }
#endif

__device__ __forceinline__ unsigned bf16_rne(float f) {   // f32 -> bf16 bits, RNE
    unsigned u = __float_as_uint(f);
    return (u + 0x7FFFu + ((u >> 16) & 1u)) >> 16;
}
__device__ __forceinline__ float wave_sum(float v) {
#pragma unroll
    for (int m = 32; m > 0; m >>= 1) v += __shfl_xor(v, m, 64);
    return v;
}

extern "C" __global__ void sk_zero_out(float* out) { out[0] = 0.0f; }

// ---------------------------------------------------------------------------
// Fully fused Sinkhorn, round-8 structure + EARLY EXIT on bf16 stationarity.
// 200 half-iterations as 16x16x32 bf16 MFMA GEMMs; once the same-parity MFMA
// result acc repeats exactly (state is bit-stationary in bf16), all further
// iterations are no-ops -> break and run the 2 capture half-iterations.
// Bit-identical to the full 200-iteration run by induction.
// Block = 16 batch rows, 4 waves; wave w owns N-tiles {2w, 2w+1} (N pad 128).
// ---------------------------------------------------------------------------
extern "C" __global__ void __launch_bounds__(256)
sk_fused(const float* __restrict__ pred, const int* __restrict__ target,
         float* __restrict__ out, int rows)
{
    __shared__ short xs[2 * XBUF];
    __shared__ __align__(16) float aux[RPB * 104];  // muL pre-loop; SsumP/zP/sclS post
    __shared__ int flagS[2][4];                     // parity-double-buffered change flags

    const int tid  = threadIdx.x;
    const int lane = tid & 63;
    const int wave = tid >> 6;        // 0..3
    const int quad = lane >> 4;       // 0..3
    const int lc   = lane & 15;
    const int row0 = blockIdx.x * RPB;

    // ---- mu = normalize(softmax(pred_row) + STAB): 16 threads per row ----
    {
        const int r = tid >> 4;       // 0..15
        const int c = tid & 15;
        const float* p = pred + (size_t)(row0 + r) * NCLS;
        float v[7];
        float mx = -3.4e38f;
#pragma unroll
        for (int q = 0; q < 7; ++q) {
            int j = c + q * 16;
            v[q] = (j < NCLS) ? p[j] : -3.4e38f;
            mx = fmaxf(mx, v[q]);
        }
#pragma unroll
        for (int m = 8; m >= 1; m >>= 1) mx = fmaxf(mx, __shfl_xor(mx, m, 64));
        float s = 0.f;
#pragma unroll
        for (int q = 0; q < 7; ++q) {
            v[q] = (c + q * 16 < NCLS) ? expf(v[q] - mx) : 0.f;
            s += v[q];
        }
#pragma unroll
        for (int m = 8; m >= 1; m >>= 1) s += __shfl_xor(s, m, 64);
        float invS = 1.f / s;
        float s2 = 0.f;
#pragma unroll
        for (int q = 0; q < 7; ++q) {
            if (c + q * 16 < NCLS) { v[q] = v[q] * invS + 1e-6f; s2 += v[q]; }
        }
#pragma unroll
        for (int m = 8; m >= 1; m >>= 1) s2 += __shfl_xor(s2, m, 64);
        float invM = 1.f / s2;
#pragma unroll
        for (int q = 0; q < 7; ++q) {
            int j = c + q * 16;
            if (j < NCLS) aux[r * 104 + j] = v[q] * invM;
        }
    }

    // ---- this wave's N-columns ----
    const int t0n = (2 * wave) * 16 + lc;
    const int t1n = (2 * wave + 1) * 16 + lc;
    const float bias0 = (t0n >= NCLS) ? 1.0f : 0.0f;   // keep rcp input > 0 on pad cols
    const float bias1 = (t1n >= NCLS) ? 1.0f : 0.0f;

    // ---- static B-fragments: B[k=quad*8+j][n] = w(k-n), bf16, Toeplitz ----
    const float c2 = -14.4269504089f / 9801.0f;        // -10*log2(e)/9801
    bf16x8 B0[4], B1[4];
#pragma unroll
    for (int s = 0; s < 4; ++s) {
#pragma unroll
        for (int j = 0; j < 8; ++j) {
            int k  = s * 32 + quad * 8 + j;
            int d0 = k - t0n;
            int d1 = k - t1n;
            B0[s][j] = (short)bf16_rne(fast_exp2(c2 * (float)(d0 * d0)));
            B1[s][j] = (short)bf16_rne(fast_exp2(c2 * (float)(d1 * d1)));
        }
    }

    __syncthreads();   // muL ready

    // ---- marginal fragments in C-layout (row m = quad*4+r, col n) ----
    f32x4 mu0f, mu1f, nu0f, nu1f;
    const float invN = 1.0f / (1.0f + (float)NCLS * 1e-6f);
#pragma unroll
    for (int r = 0; r < 4; ++r) {
        int m = quad * 4 + r;
        mu0f[r] = (t0n < NCLS) ? aux[m * 104 + t0n] : 0.f;
        mu1f[r] = (t1n < NCLS) ? aux[m * 104 + t1n] : 0.f;
        int tg = (int)target[row0 + m];
        nu0f[r] = (t0n < NCLS) ? ((((t0n == tg) ? 1.f : 0.f) + 1e-6f) * invN) : 0.f;
        nu1f[r] = (t1n < NCLS) ? ((((t1n == tg) ? 1.f : 0.f) + 1e-6f) * invN) : 0.f;
    }

    // ---- init x = b0 = 1 (cols < 100), 0 on pad cols; buffer 0 ----
    {
        const short one = (short)0x3F80;   // bf16(1.0)
#pragma unroll
        for (int r = 0; r < 4; ++r) {
            int m = quad * 4 + r;
            xs[m * XS + t0n] = (t0n < NCLS) ? one : (short)0;
            xs[m * XS + t1n] = (t1n < NCLS) ? one : (short)0;
        }
    }
    __syncthreads();

    // ---- main loop (up to 198 half-iters) with stationarity early-exit ----
    f32x4 pv0[2], pv1[2];   // previous same-parity acc
    pv0[0] = (f32x4){-1.f, -1.f, -1.f, -1.f}; pv0[1] = pv0[0];
    pv1[0] = pv0[0];                           pv1[1] = pv0[0];
    int sc = 0;
    int it = 0;
    for (; it < 2 * ITERS - 2; ++it) {
        const short* cur = xs + (it & 1) * XBUF;
        short*       nxt = xs + ((it + 1) & 1) * XBUF;

        bf16x8 A[4];
#pragma unroll
        for (int s = 0; s < 4; ++s)
            A[s] = *(const bf16x8*)(cur + lc * XS + s * 32 + quad * 8);

        f32x4 acc0 = {0.f, 0.f, 0.f, 0.f};
        f32x4 acc1 = {0.f, 0.f, 0.f, 0.f};
#pragma unroll
        for (int s = 0; s < 4; ++s) {
            acc0 = __builtin_amdgcn_mfma_f32_16x16x32_bf16(A[s], B0[s], acc0, 0, 0, 0);
            acc1 = __builtin_amdgcn_mfma_f32_16x16x32_bf16(A[s], B1[s], acc1, 0, 0, 0);
        }

        const int par = it & 1;
        bool chg = false;
#pragma unroll
        for (int r = 0; r < 4; ++r)
            chg = chg || (acc0[r] != pv0[par][r]) || (acc1[r] != pv1[par][r]);
        pv0[par] = acc0; pv1[par] = acc1;
        int anyv = __any((int)chg);

        const bool odd = par != 0;
#pragma unroll
        for (int r = 0; r < 4; ++r) {
            int m = quad * 4 + r;
            float mg0 = odd ? nu0f[r] : mu0f[r];
            float mg1 = odd ? nu1f[r] : mu1f[r];
            float x0 = mg0 * fast_rcp(acc0[r] + bias0);
            float x1 = mg1 * fast_rcp(acc1[r] + bias1);
            nxt[m * XS + t0n] = (short)bf16_rne(x0);
            nxt[m * XS + t1n] = (short)bf16_rne(x1);
        }
        if (lane == 0) flagS[par][wave] = anyv;
        __syncthreads();
        int bc = flagS[par][0] | flagS[par][1] | flagS[par][2] | flagS[par][3];
        sc = bc ? 0 : (sc + 1);
        if (sc >= 2 && par == 1) { ++it; break; }   // exit after an odd half-iter
    }

    // ---- capture phase: exactly 2 more half-iters (even -> a, odd -> b) ----
    f32x4 aR0, aR1, bR0, bR1;
    for (int cap = 0; cap < 2; ++cap, ++it) {
        const short* cur = xs + (it & 1) * XBUF;
        short*       nxt = xs + ((it + 1) & 1) * XBUF;

        bf16x8 A[4];
#pragma unroll
        for (int s = 0; s < 4; ++s)
            A[s] = *(const bf16x8*)(cur + lc * XS + s * 32 + quad * 8);

        f32x4 acc0 = {0.f, 0.f, 0.f, 0.f};
        f32x4 acc1 = {0.f, 0.f, 0.f, 0.f};
#pragma unroll
        for (int s = 0; s < 4; ++s) {
            acc0 = __builtin_amdgcn_mfma_f32_16x16x32_bf16(A[s], B0[s], acc0, 0, 0, 0);
            acc1 = __builtin_amdgcn_mfma_f32_16x16x32_bf16(A[s], B1[s], acc1, 0, 0, 0);
        }

        const bool odd = cap != 0;   // first capture half-iter is even (a)
#pragma unroll
        for (int r = 0; r < 4; ++r) {
            int m = quad * 4 + r;
            float mg0 = odd ? nu0f[r] : mu0f[r];
            float mg1 = odd ? nu1f[r] : mu1f[r];
            float x0 = mg0 * fast_rcp(acc0[r] + bias0);
            float x1 = mg1 * fast_rcp(acc1[r] + bias1);
            nxt[m * XS + t0n] = (short)bf16_rne(x0);
            nxt[m * XS + t1n] = (short)bf16_rne(x1);
            if (!odd) { aR0[r] = x0; aR1[r] = x1; }   // final a (fp32)
            else      { bR0[r] = x0; bR1[r] = x1; }   // final b (fp32)
        }
        __syncthreads();
    }
    // b (bf16) now in buffer 0; a dead (aR in regs).

    // ================= fused epilogue =================
    // t = K b  (same MFMA pattern, A from buffer 0)
    f32x4 t0a = {0.f, 0.f, 0.f, 0.f};
    f32x4 t1a = {0.f, 0.f, 0.f, 0.f};
    {
        bf16x8 A[4];
#pragma unroll
        for (int s = 0; s < 4; ++s)
            A[s] = *(const bf16x8*)(xs + lc * XS + s * 32 + quad * 8);
#pragma unroll
        for (int s = 0; s < 4; ++s) {
            t0a = __builtin_amdgcn_mfma_f32_16x16x32_bf16(A[s], B0[s], t0a, 0, 0, 0);
            t1a = __builtin_amdgcn_mfma_f32_16x16x32_bf16(A[s], B1[s], t1a, 0, 0, 0);
        }
    }

    // scl = mu / (a*t + n*STAB);  a' = a*scl.  Write a' (buf1) and scl bf16.
    float* SsumP = aux;                     // [4 waves][16 m] floats (256 B)
    float* zP    = aux + 64;                // [4] block-reduce slots
    short* sclS  = (short*)(aux + 128);     // [RPB][XS] bf16 (4352 B)
    short* apS   = xs + XBUF;               // buffer 1, a dead

#pragma unroll
    for (int r = 0; r < 4; ++r) {
        int m = quad * 4 + r;
        float scl0 = mu0f[r] * fast_rcp(fmaf(aR0[r], t0a[r], (float)NCLS * 1e-6f));
        float scl1 = mu1f[r] * fast_rcp(fmaf(aR1[r], t1a[r], (float)NCLS * 1e-6f));
        apS[m * XS + t0n]  = (short)bf16_rne(aR0[r] * scl0);
        apS[m * XS + t1n]  = (short)bf16_rne(aR1[r] * scl1);
        sclS[m * XS + t0n] = (short)bf16_rne(scl0);
        sclS[m * XS + t1n] = (short)bf16_rne(scl1);
        // partial Ssum over this wave's 32 cols (16-lane quad reduce)
        float ps = scl0 + scl1;
#pragma unroll
        for (int w = 8; w >= 1; w >>= 1) ps += __shfl_xor(ps, w, 64);
        if (lc == 0) SsumP[wave * 16 + m] = ps;
    }
    __syncthreads();

    // Ssum[m] = sum over 4 waves
    f32x4 Ssum;
#pragma unroll
    for (int r = 0; r < 4; ++r) {
        int m = quad * 4 + r;
        Ssum[r] = SsumP[m] + SsumP[16 + m] + SsumP[32 + m] + SsumP[48 + m];
    }

    // B-frags for K.C and C (Toeplitz): KC(d) = K(d)*d^2/9801, C(d) = d^2/9801
    bf16x8 KC0[4], KC1[4], C0[4], C1[4];
    const float cinv = 1.0f / 9801.0f;
#pragma unroll
    for (int s = 0; s < 4; ++s) {
#pragma unroll
        for (int j = 0; j < 8; ++j) {
            int k  = s * 32 + quad * 8 + j;
            int d0 = k - t0n;
            int d1 = k - t1n;
            float c0 = (float)(d0 * d0) * cinv;
            float c1 = (float)(d1 * d1) * cinv;
            KC0[s][j] = (short)bf16_rne(fast_exp2(c2 * (float)(d0 * d0)) * c0);
            KC1[s][j] = (short)bf16_rne(fast_exp2(c2 * (float)(d1 * d1)) * c1);
            C0[s][j]  = (short)bf16_rne(c0);
            C1[s][j]  = (short)bf16_rne(c1);
        }
    }

    // q = K a',  mm = (K.C) a',  cs = C scl   (A-frags from apS / sclS)
    f32x4 q0 = {0,0,0,0}, q1 = {0,0,0,0};
    f32x4 m0 = {0,0,0,0}, m1 = {0,0,0,0};
    f32x4 s0 = {0,0,0,0}, s1 = {0,0,0,0};
    {
        bf16x8 Aa[4], As[4];
#pragma unroll
        for (int s = 0; s < 4; ++s) {
            Aa[s] = *(const bf16x8*)(apS  + lc * XS + s * 32 + quad * 8);
            As[s] = *(const bf16x8*)(sclS + lc * XS + s * 32 + quad * 8);
        }
#pragma unroll
        for (int s = 0; s < 4; ++s) {
            q0 = __builtin_amdgcn_mfma_f32_16x16x32_bf16(Aa[s], B0[s],  q0, 0, 0, 0);
            q1 = __builtin_amdgcn_mfma_f32_16x16x32_bf16(Aa[s], B1[s],  q1, 0, 0, 0);
            m0 = __builtin_amdgcn_mfma_f32_16x16x32_bf16(Aa[s], KC0[s], m0, 0, 0, 0);
            m1 = __builtin_amdgcn_mfma_f32_16x16x32_bf16(Aa[s], KC1[s], m1, 0, 0, 0);
            s0 = __builtin_amdgcn_mfma_f32_16x16x32_bf16(As[s], C0[s],  s0, 0, 0, 0);
            s1 = __builtin_amdgcn_mfma_f32_16x16x32_bf16(As[s], C1[s],  s1, 0, 0, 0);
        }
    }

    // cost: z = sum_j nu_j/(b_j q_j + STAB*Ssum) * (b_j mm_j + STAB*cs_j)
    float z = 0.f;
#pragma unroll
    for (int r = 0; r < 4; ++r) {
        float col0 = fmaf(bR0[r], q0[r], 1e-6f * Ssum[r]);
        float col1 = fmaf(bR1[r], q1[r], 1e-6f * Ssum[r]);
        float in0  = fmaf(bR0[r], m0[r], 1e-6f * s0[r]);
        float in1  = fmaf(bR1[r], m1[r], 1e-6f * s1[r]);
        z += nu0f[r] * fast_rcp(col0) * in0 + nu1f[r] * fast_rcp(col1) * in1;
    }
    z = wave_sum(z);
    if (lane == 0) zP[wave] = z;
    __syncthreads();
    if (tid == 0) {
        float tot = zP[0] + zP[1] + zP[2] + zP[3];
        atomicAdd(out, tot / (float)rows);
    }
}

extern "C" void kernel_launch(void* const* d_in, const int* in_sizes, int n_in,
                              void* d_out, int out_size, void* d_ws, size_t ws_size,
                              hipStream_t stream)
{
    const float* pred   = (const float*)d_in[0];
    const int*   target = (const int*)d_in[1];
    float*       out    = (float*)d_out;
    const int    rows   = in_sizes[0] / NCLS;   // 4096

    hipLaunchKernelGGL(sk_zero_out, dim3(1), dim3(1), 0, stream, out);
    hipLaunchKernelGGL(sk_fused, dim3(rows / RPB), dim3(256), 0, stream,
                       pred, target, out, rows);
}

// Round 11
// 68.837 us; speedup vs baseline: 7.5660x; 1.0741x over previous
//
#include <hip/hip_runtime.h>
#include <math.h>

#define NCLS   100
#define ITERS  100
#define RPB    16            // batch rows per block (MFMA M)
#define XS     136           // LDS x row stride, bf16 elems
#define XBUF   (RPB * XS)

typedef short  bf16x8 __attribute__((ext_vector_type(8)));   // 8 bf16 in 4 VGPRs
typedef float  f32x4  __attribute__((ext_vector_type(4)));

#if __has_builtin(__builtin_amdgcn_rcpf)
__device__ __forceinline__ float fast_rcp(float x) { return __builtin_amdgcn_rcpf(x); }
#else
__device__ __forceinline__ float fast_rcp(float x) { return 1.0f / x; }
#endif

#if __has_builtin(__builtin_amdgcn_exp2f)
__device__ __forceinline__ float fast_exp2(float x) { return __builtin_amdgcn_exp2f(x); }
#else
__device__ __forceinline__ float fast_exp2(float x) { return exp2f(x); }
#endif

__device__ __forceinline__ unsigned bf16_rne(float f) {   // f32 -> bf16 bits, RNE
    unsigned u = __float_as_uint(f);
    return (u + 0x7FFFu + ((u >> 16) & 1u)) >> 16;
}
__device__ __forceinline__ float wave_sum(float v) {
#pragma unroll
    for (int m = 32; m > 0; m >>= 1) v += __shfl_xor(v, m, 64);
    return v;
}
__device__ __forceinline__ bool any_ne(f32x4 a, f32x4 b) {
    return (a[0] != b[0]) | (a[1] != b[1]) | (a[2] != b[2]) | (a[3] != b[3]);
}

#define MFMA_B(Af, Bf, Cf) __builtin_amdgcn_mfma_f32_16x16x32_bf16(Af, Bf, Cf, 0, 0, 0)

extern "C" __global__ void sk_zero_out(float* out) { out[0] = 0.0f; }

// One Sinkhorn half-iteration: X = MG ⊘ (K x_src); writes bf16 X to DST,
// exports fp32 X into X0V/X1V and the raw MFMA accs into accP0_/accP1_.
// Four 2-deep MFMA chains (shorter dep chain than 2x4).
#define HALF(SRC, DST, MG0, MG1, X0V, X1V)                                   \
    {                                                                        \
        bf16x8 A_[4];                                                        \
        _Pragma("unroll")                                                    \
        for (int s_ = 0; s_ < 4; ++s_)                                       \
            A_[s_] = *(const bf16x8*)((SRC) + lc * XS + s_ * 32 + quad * 8); \
        f32x4 aA_ = {0,0,0,0}, aB_ = {0,0,0,0};                              \
        f32x4 bA_ = {0,0,0,0}, bB_ = {0,0,0,0};                              \
        aA_ = MFMA_B(A_[0], B0[0], aA_);  bA_ = MFMA_B(A_[0], B1[0], bA_);   \
        aB_ = MFMA_B(A_[2], B0[2], aB_);  bB_ = MFMA_B(A_[2], B1[2], bB_);   \
        aA_ = MFMA_B(A_[1], B0[1], aA_);  bA_ = MFMA_B(A_[1], B1[1], bA_);   \
        aB_ = MFMA_B(A_[3], B0[3], aB_);  bB_ = MFMA_B(A_[3], B1[3], bB_);   \
        f32x4 acc0_ = aA_ + aB_;                                             \
        f32x4 acc1_ = bA_ + bB_;                                             \
        _Pragma("unroll")                                                    \
        for (int r_ = 0; r_ < 4; ++r_) {                                     \
            int m_ = quad * 4 + r_;                                          \
            X0V[r_] = MG0[r_] * fast_rcp(acc0_[r_] + bias0);                 \
            X1V[r_] = MG1[r_] * fast_rcp(acc1_[r_] + bias1);                 \
            (DST)[m_ * XS + t0n] = (short)bf16_rne(X0V[r_]);                 \
            (DST)[m_ * XS + t1n] = (short)bf16_rne(X1V[r_]);                 \
        }                                                                    \
        accP0_ = acc0_; accP1_ = acc1_;                                      \
    }

// ---------------------------------------------------------------------------
// Fully fused Sinkhorn (round-10 structure) + warm start b0 = nu.
// Early exit when a full (even,odd) pair's MFMA accs are bit-stationary in
// bf16 -> all further pairs are no-ops. Warm start changes only the scale
// member (a,b)->(c a, b/c) of the fixed-point family; the renorm epilogue is
// exactly scale-invariant, so the cost matches to fp rounding.
// Block = 16 batch rows, 4 waves; wave w owns N-tiles {2w, 2w+1} (N pad 128).
// ---------------------------------------------------------------------------
extern "C" __global__ void __launch_bounds__(256)
sk_fused(const float* __restrict__ pred, const int* __restrict__ target,
         float* __restrict__ out, int rows)
{
    __shared__ short xs[2 * XBUF];
    __shared__ __align__(16) float aux[RPB * 104];  // muL pre-loop; SsumP/zP/sclS post
    __shared__ int flagS[4];                        // per-wave change flags (1/pair)

    const int tid  = threadIdx.x;
    const int lane = tid & 63;
    const int wave = tid >> 6;        // 0..3
    const int quad = lane >> 4;       // 0..3
    const int lc   = lane & 15;
    const int row0 = blockIdx.x * RPB;

    // ---- mu = normalize(softmax(pred_row) + STAB): 16 threads per row ----
    {
        const int r = tid >> 4;       // 0..15
        const int c = tid & 15;
        const float* p = pred + (size_t)(row0 + r) * NCLS;
        const float l2e = 1.44269504089f;
        float v[7];
        float mx = -3.4e38f;
#pragma unroll
        for (int q = 0; q < 7; ++q) {
            int j = c + q * 16;
            v[q] = (j < NCLS) ? p[j] : -3.4e38f;
            mx = fmaxf(mx, v[q]);
        }
#pragma unroll
        for (int m = 8; m >= 1; m >>= 1) mx = fmaxf(mx, __shfl_xor(mx, m, 64));
        float s = 0.f;
#pragma unroll
        for (int q = 0; q < 7; ++q) {
            v[q] = (c + q * 16 < NCLS) ? fast_exp2((v[q] - mx) * l2e) : 0.f;
            s += v[q];
        }
#pragma unroll
        for (int m = 8; m >= 1; m >>= 1) s += __shfl_xor(s, m, 64);
        float invS = 1.f / s;
        float s2 = 0.f;
#pragma unroll
        for (int q = 0; q < 7; ++q) {
            if (c + q * 16 < NCLS) { v[q] = v[q] * invS + 1e-6f; s2 += v[q]; }
        }
#pragma unroll
        for (int m = 8; m >= 1; m >>= 1) s2 += __shfl_xor(s2, m, 64);
        float invM = 1.f / s2;
#pragma unroll
        for (int q = 0; q < 7; ++q) {
            int j = c + q * 16;
            if (j < NCLS) aux[r * 104 + j] = v[q] * invM;
        }
    }

    // ---- this wave's N-columns ----
    const int t0n = (2 * wave) * 16 + lc;
    const int t1n = (2 * wave + 1) * 16 + lc;
    const float bias0 = (t0n >= NCLS) ? 1.0f : 0.0f;   // keep rcp input > 0 on pad cols
    const float bias1 = (t1n >= NCLS) ? 1.0f : 0.0f;

    // ---- static B-fragments: B[k=quad*8+j][n] = w(k-n), bf16, Toeplitz ----
    const float c2 = -14.4269504089f / 9801.0f;        // -10*log2(e)/9801
    bf16x8 B0[4], B1[4];
#pragma unroll
    for (int s = 0; s < 4; ++s) {
#pragma unroll
        for (int j = 0; j < 8; ++j) {
            int k  = s * 32 + quad * 8 + j;
            int d0 = k - t0n;
            int d1 = k - t1n;
            B0[s][j] = (short)bf16_rne(fast_exp2(c2 * (float)(d0 * d0)));
            B1[s][j] = (short)bf16_rne(fast_exp2(c2 * (float)(d1 * d1)));
        }
    }

    __syncthreads();   // muL ready

    // ---- marginal fragments in C-layout (row m = quad*4+r, col n) ----
    f32x4 mu0f, mu1f, nu0f, nu1f;
    const float invN = 1.0f / (1.0f + (float)NCLS * 1e-6f);
#pragma unroll
    for (int r = 0; r < 4; ++r) {
        int m = quad * 4 + r;
        mu0f[r] = (t0n < NCLS) ? aux[m * 104 + t0n] : 0.f;
        mu1f[r] = (t1n < NCLS) ? aux[m * 104 + t1n] : 0.f;
        int tg = (int)target[row0 + m];
        nu0f[r] = (t0n < NCLS) ? ((((t0n == tg) ? 1.f : 0.f) + 1e-6f) * invN) : 0.f;
        nu1f[r] = (t1n < NCLS) ? ((((t1n == tg) ? 1.f : 0.f) + 1e-6f) * invN) : 0.f;
    }

    // ---- WARM START: x = b0 = nu (pad cols 0); buffer 0 ----
#pragma unroll
    for (int r = 0; r < 4; ++r) {
        int m = quad * 4 + r;
        xs[m * XS + t0n] = (short)bf16_rne(nu0f[r]);
        xs[m * XS + t1n] = (short)bf16_rne(nu1f[r]);
    }
    __syncthreads();

    // ---- main pair loop with stationarity early-exit (<= 99 pairs) ----
    f32x4 pvE0 = {-1.f,-1.f,-1.f,-1.f}, pvE1 = pvE0, pvO0 = pvE0, pvO1 = pvE0;
    f32x4 xT0, xT1, accP0_, accP1_;
    for (int pair = 0; pair < ITERS - 1; ++pair) {
        // even half: a = mu/(K b), buf0 -> buf1
        HALF(xs, xs + XBUF, mu0f, mu1f, xT0, xT1);
        bool chgE = any_ne(accP0_, pvE0) || any_ne(accP1_, pvE1);
        pvE0 = accP0_; pvE1 = accP1_;
        __syncthreads();
        // odd half: b = nu/(K a), buf1 -> buf0
        HALF(xs + XBUF, xs, nu0f, nu1f, xT0, xT1);
        bool chgO = any_ne(accP0_, pvO0) || any_ne(accP1_, pvO1);
        pvO0 = accP0_; pvO1 = accP1_;
        int anyv = __any((int)(chgE || chgO));
        if (lane == 0) flagS[wave] = anyv;
        __syncthreads();
        if ((flagS[0] | flagS[1] | flagS[2] | flagS[3]) == 0) break;
    }

    // ---- capture pair: final a (fp32) and b (fp32); b bf16 lands in buf0 ----
    f32x4 aR0, aR1, bR0, bR1;
    HALF(xs, xs + XBUF, mu0f, mu1f, aR0, aR1);
    __syncthreads();
    HALF(xs + XBUF, xs, nu0f, nu1f, bR0, bR1);
    __syncthreads();

    // ================= fused epilogue (round-10-verified math) =================
    // t = K b  (A from buffer 0)
    f32x4 t0a = {0.f, 0.f, 0.f, 0.f};
    f32x4 t1a = {0.f, 0.f, 0.f, 0.f};
    {
        bf16x8 A[4];
#pragma unroll
        for (int s = 0; s < 4; ++s)
            A[s] = *(const bf16x8*)(xs + lc * XS + s * 32 + quad * 8);
#pragma unroll
        for (int s = 0; s < 4; ++s) {
            t0a = MFMA_B(A[s], B0[s], t0a);
            t1a = MFMA_B(A[s], B1[s], t1a);
        }
    }

    // scl = mu / (a*t + n*STAB);  a' = a*scl.  Write a' (buf1) and scl bf16.
    float* SsumP = aux;                     // [4 waves][16 m] floats (256 B)
    float* zP    = aux + 64;                // [4] block-reduce slots
    short* sclS  = (short*)(aux + 128);     // [RPB][XS] bf16 (4352 B)
    short* apS   = xs + XBUF;               // buffer 1, a dead

#pragma unroll
    for (int r = 0; r < 4; ++r) {
        int m = quad * 4 + r;
        float scl0 = mu0f[r] * fast_rcp(fmaf(aR0[r], t0a[r], (float)NCLS * 1e-6f));
        float scl1 = mu1f[r] * fast_rcp(fmaf(aR1[r], t1a[r], (float)NCLS * 1e-6f));
        apS[m * XS + t0n]  = (short)bf16_rne(aR0[r] * scl0);
        apS[m * XS + t1n]  = (short)bf16_rne(aR1[r] * scl1);
        sclS[m * XS + t0n] = (short)bf16_rne(scl0);
        sclS[m * XS + t1n] = (short)bf16_rne(scl1);
        // partial Ssum over this wave's 32 cols (16-lane quad reduce)
        float ps = scl0 + scl1;
#pragma unroll
        for (int w = 8; w >= 1; w >>= 1) ps += __shfl_xor(ps, w, 64);
        if (lc == 0) SsumP[wave * 16 + m] = ps;
    }
    __syncthreads();

    // Ssum[m] = sum over 4 waves
    f32x4 Ssum;
#pragma unroll
    for (int r = 0; r < 4; ++r) {
        int m = quad * 4 + r;
        Ssum[r] = SsumP[m] + SsumP[16 + m] + SsumP[32 + m] + SsumP[48 + m];
    }

    // B-frags for K.C and C (Toeplitz): KC(d) = K(d)*d^2/9801, C(d) = d^2/9801
    bf16x8 KC0[4], KC1[4], C0[4], C1[4];
    const float cinv = 1.0f / 9801.0f;
#pragma unroll
    for (int s = 0; s < 4; ++s) {
#pragma unroll
        for (int j = 0; j < 8; ++j) {
            int k  = s * 32 + quad * 8 + j;
            int d0 = k - t0n;
            int d1 = k - t1n;
            float c0 = (float)(d0 * d0) * cinv;
            float c1 = (float)(d1 * d1) * cinv;
            KC0[s][j] = (short)bf16_rne(fast_exp2(c2 * (float)(d0 * d0)) * c0);
            KC1[s][j] = (short)bf16_rne(fast_exp2(c2 * (float)(d1 * d1)) * c1);
            C0[s][j]  = (short)bf16_rne(c0);
            C1[s][j]  = (short)bf16_rne(c1);
        }
    }

    // q = K a',  mm = (K.C) a',  cs = C scl   (A-frags from apS / sclS)
    f32x4 q0 = {0,0,0,0}, q1 = {0,0,0,0};
    f32x4 m0 = {0,0,0,0}, m1 = {0,0,0,0};
    f32x4 s0 = {0,0,0,0}, s1 = {0,0,0,0};
    {
        bf16x8 Aa[4], As[4];
#pragma unroll
        for (int s = 0; s < 4; ++s) {
            Aa[s] = *(const bf16x8*)(apS  + lc * XS + s * 32 + quad * 8);
            As[s] = *(const bf16x8*)(sclS + lc * XS + s * 32 + quad * 8);
        }
#pragma unroll
        for (int s = 0; s < 4; ++s) {
            q0 = MFMA_B(Aa[s], B0[s],  q0);
            q1 = MFMA_B(Aa[s], B1[s],  q1);
            m0 = MFMA_B(Aa[s], KC0[s], m0);
            m1 = MFMA_B(Aa[s], KC1[s], m1);
            s0 = MFMA_B(As[s], C0[s],  s0);
            s1 = MFMA_B(As[s], C1[s],  s1);
        }
    }

    // cost: z = sum_j nu_j/(b_j q_j + STAB*Ssum) * (b_j mm_j + STAB*cs_j)
    float z = 0.f;
#pragma unroll
    for (int r = 0; r < 4; ++r) {
        float col0 = fmaf(bR0[r], q0[r], 1e-6f * Ssum[r]);
        float col1 = fmaf(bR1[r], q1[r], 1e-6f * Ssum[r]);
        float in0  = fmaf(bR0[r], m0[r], 1e-6f * s0[r]);
        float in1  = fmaf(bR1[r], m1[r], 1e-6f * s1[r]);
        z += nu0f[r] * fast_rcp(col0) * in0 + nu1f[r] * fast_rcp(col1) * in1;
    }
    z = wave_sum(z);
    if (lane == 0) zP[wave] = z;
    __syncthreads();
    if (tid == 0) {
        float tot = zP[0] + zP[1] + zP[2] + zP[3];
        atomicAdd(out, tot / (float)rows);
    }
}

extern "C" void kernel_launch(void* const* d_in, const int* in_sizes, int n_in,
                              void* d_out, int out_size, void* d_ws, size_t ws_size,
                              hipStream_t stream)
{
    const float* pred   = (const float*)d_in[0];
    const int*   target = (const int*)d_in[1];
    float*       out    = (float*)d_out;
    const int    rows   = in_sizes[0] / NCLS;   // 4096

    hipLaunchKernelGGL(sk_zero_out, dim3(1), dim3(1), 0, stream, out);
    hipLaunchKernelGGL(sk_fused, dim3(rows / RPB), dim3(256), 0, stream,
                       pred, target, out, rows);
}